// Round 24
// baseline (81.055 us; speedup 1.0000x reference)
//
#include <hip/hip_runtime.h>
#include <hip/hip_bf16.h>
#include <math.h>

typedef __attribute__((ext_vector_type(8))) short short8v;   // 8 bf16 bits
typedef __attribute__((ext_vector_type(4))) float f32x4;     // 16x16 MFMA acc

__device__ __forceinline__ unsigned short f2bf(float x) {
    union { float f; unsigned u; } v; v.f = x;
    unsigned r = v.u + 0x7FFF + ((v.u >> 16) & 1);   // RNE
    return (unsigned short)(r >> 16);
}
__device__ __forceinline__ unsigned cvtpk(float a, float b) {
    unsigned short lo = __builtin_bit_cast(unsigned short, __float2bfloat16(a));
    unsigned short hi = __builtin_bit_cast(unsigned short, __float2bfloat16(b));
    return (unsigned)lo | ((unsigned)hi << 16);
}
__device__ __forceinline__ float fast_tanh(float x) {
    float e = __expf(2.0f * x);
    return 1.0f - 2.0f / (e + 1.0f);
}
// sigma(ct,p) = 32*(ct>>1) + 8*(p>>2) + 4*(ct&1) + (p&3); row = ct*16+p.
// Inverse (R22/R23-verified): col bits [c2 c1 p3 p2 c0 p1 p0]
__device__ __forceinline__ int sigma_inv_row(int col) {
    int ct = ((col >> 4) & 6) | ((col >> 2) & 1);
    int p  = ((col >> 1) & 12) | (col & 3);
    return ct * 16 + p;
}

// SLIM LDS table layout (shorts). K=16 zero-padding moved to the B operand
// (masked xb/vb in kg>=2 lanes), so W1/MP need no zero rows:
//   T_W1  [128 row][16]   = W1[k][sigma]           (2048 sh)
//   T_W2  [128 row][136]  k<128 = W2[k][sigma]     (17408 sh)
//   T_W3  [16 col][136]   k<128 = W3[k][col]       (2176 sh)
//   T_MP  [128 row][16]   = MP val                 (2048 sh)
//   +16 slack for kg=3,m=15 fragment overhang (garbage x B-zero = harmless)
#define T_W1    0
#define T_W2    2048
#define T_W3    19456
#define T_MP    21632
#define T_SH    23680

// ---------------------------------------------------------------------------
// SINGLE kernel (R23 + slim tables + B-side K-masking -> 3 blocks/CU).
// 512 thr, 256 elems/block (dual tile), grid = 512.
// ---------------------------------------------------------------------------
__global__ __launch_bounds__(512) void ce_all(
    const float* __restrict__ Y, const float* __restrict__ Xp,
    const int* __restrict__ pilot_pos,
    const float* __restrict__ W1, const float* __restrict__ b1,
    const float* __restrict__ W2, const float* __restrict__ b2,
    const float* __restrict__ W3, const float* __restrict__ b3,
    const float* __restrict__ est_w, const float* __restrict__ alpha,
    const float* __restrict__ decay_param,
    const float* __restrict__ window_logits,
    float* __restrict__ out, int B)
{
    __shared__ unsigned short sT[T_SH + 16];     // 47424 B
    __shared__ float sA[64 * 16];                // 4096 B
    __shared__ float Gr[64], Gi[64], wln[64], wrn[64];
    __shared__ int lefts[64];

    const int t = threadIdx.x;
    const int w = t >> 6, l = t & 63;
    const int m = l & 15, kg = l >> 4;
    const int tl = kg >> 1, pg = kg & 1;
    const bool act = (kg < 2);
    const long base = (long)blockIdx.x * 256 + w * 32;

    typedef union { unsigned u[4]; short8v v; } pk_t;
    const f32x4 z4 = {0.f, 0.f, 0.f, 0.f};
    const short8v zz8 = {0, 0, 0, 0, 0, 0, 0, 0};

    // ---- gather (ALL 64 lanes) issued first; hides under table build ----
    long e_g = base + tl * 16 + m;
    long e_gc = (e_g < B) ? e_g : (long)(B - 1);
    const float* yrow = Y + e_gc * 128;
    const float4* xr = (const float4*)(Xp + e_gc * 16 + pg * 8);
    int p0 = pg * 4;
    float2 y0 = *(const float2*)(yrow + pilot_pos[p0 + 0] * 2);
    float2 y1 = *(const float2*)(yrow + pilot_pos[p0 + 1] * 2);
    float2 y2 = *(const float2*)(yrow + pilot_pos[p0 + 2] * 2);
    float2 y3 = *(const float2*)(yrow + pilot_pos[p0 + 3] * 2);
    float4 x0 = xr[0], x1 = xr[1];

    // ---- stage W1/W2/W3: float4 global reads, scattered LDS writes ----
    {   // W1: 2048 floats = 512 float4 -> one per thread
        float4 v = ((const float4*)W1)[t];
        int k = t >> 5, c4 = (t & 31) * 4;
        sT[T_W1 + sigma_inv_row(c4 + 0) * 16 + k] = f2bf(v.x);
        sT[T_W1 + sigma_inv_row(c4 + 1) * 16 + k] = f2bf(v.y);
        sT[T_W1 + sigma_inv_row(c4 + 2) * 16 + k] = f2bf(v.z);
        sT[T_W1 + sigma_inv_row(c4 + 3) * 16 + k] = f2bf(v.w);
    }
    #pragma unroll
    for (int ii = 0; ii < 8; ++ii) {   // W2: 4096 float4
        int i = ii * 512 + t;
        float4 v = ((const float4*)W2)[i];
        int k = i >> 5, c4 = (i & 31) * 4;
        sT[T_W2 + sigma_inv_row(c4 + 0) * 136 + k] = f2bf(v.x);
        sT[T_W2 + sigma_inv_row(c4 + 1) * 136 + k] = f2bf(v.y);
        sT[T_W2 + sigma_inv_row(c4 + 2) * 136 + k] = f2bf(v.z);
        sT[T_W2 + sigma_inv_row(c4 + 3) * 136 + k] = f2bf(v.w);
    }
    {   // W3 cols 0..15: 128 rows x 4 float4 = 512 -> one per thread
        int k = t >> 2, c4 = (t & 3) * 4;
        float4 v = *(const float4*)(W3 + k * 64 + c4);
        sT[T_W3 + (c4 + 0) * 136 + k] = f2bf(v.x);
        sT[T_W3 + (c4 + 1) * 136 + k] = f2bf(v.y);
        sT[T_W3 + (c4 + 2) * 136 + k] = f2bf(v.z);
        sT[T_W3 + (c4 + 3) * 136 + k] = f2bf(v.w);
    }
    if (t < 16) sT[T_SH + t] = 0;   // slack

    // ---- LS compute + pack (|Xp|=1 -> no division; R22/R23-proven) ----
    float lsv[8];
    {
        lsv[0] = y0.x * x0.x + y0.y * x0.y;
        lsv[1] = y0.y * x0.x - y0.x * x0.y;
        lsv[2] = y1.x * x0.z + y1.y * x0.w;
        lsv[3] = y1.y * x0.z - y1.x * x0.w;
        lsv[4] = y2.x * x1.x + y2.y * x1.y;
        lsv[5] = y2.y * x1.x - y2.x * x1.y;
        lsv[6] = y3.x * x1.z + y3.y * x1.w;
        lsv[7] = y3.y * x1.z - y3.x * x1.w;
    }
    pk_t px;
    px.u[0] = cvtpk(lsv[0], lsv[1]);
    px.u[1] = cvtpk(lsv[2], lsv[3]);
    px.u[2] = cvtpk(lsv[4], lsv[5]);
    px.u[3] = cvtpk(lsv[6], lsv[7]);
    short8v xb = px.v;
    short8v xb1;
    {
        union { short8v v; int i[4]; } ua, ub;
        ua.v = xb;
        #pragma unroll
        for (int q = 0; q < 4; ++q) ub.i[q] = __shfl_xor(ua.i[q], 32);
        xb1 = ub.v;
    }
    // B-side K=16 masking (replaces the A-side zero rows):
    short8v xb0m = act ? xb : zz8;
    short8v xb1m = act ? xb1 : zz8;

    // ---- A/MP build: WAVE 0 ONLY (t<64), intra-wave LDS ordering ----
    if (t < 64) {
        float decay = log1pf(expf(decay_param[0]));
        float winv[8];
        int posv[8];
        #pragma unroll
        for (int n = 0; n < 8; ++n) {
            winv[n] = 1.0f / (1.0f + expf(-window_logits[n]));
            posv[n] = pilot_pos[n];
        }
        float gr = 0.f, gi = 0.f;
        #pragma unroll
        for (int n = 0; n < 8; ++n) {
            float ang = 6.283185307179586f * (float)(n * t) * (1.0f / 64.0f);
            gr += winv[n] * cosf(ang);
            gi += winv[n] * sinf(ang);
        }
        Gr[t] = gr * (1.0f / 64.0f);
        Gi[t] = gi * (1.0f / 64.0f);
        int lft = 0;
        #pragma unroll
        for (int p = 1; p < 8; ++p) if (posv[p] <= t) lft = p;
        if (lft > 6) lft = 6;
        float xx0 = (float)posv[lft], xx1 = (float)posv[lft + 1], fi = (float)t;
        float wl = expf(-decay * fabsf(fi - xx0));
        float wr = expf(-decay * fabsf(xx1 - fi));
        float wsum = wl + wr + 1e-12f;
        lefts[t] = lft; wln[t] = wl / wsum; wrn[t] = wr / wsum;
    }
    asm volatile("s_waitcnt lgkmcnt(0)" ::: "memory");
    __builtin_amdgcn_sched_barrier(0);
    if (t < 64) {
        float ar[8], ai[8];
        for (int p = 0; p < 8; ++p) { ar[p] = 0.f; ai[p] = 0.f; }
        for (int i = 0; i < 64; ++i) {
            int d = (i - t) & 63;
            float gr = Gr[d], gi = Gi[d];
            int lft = lefts[i];
            float wa = wln[i], wb = wrn[i];
            ar[lft]     += wa * gr;  ai[lft]     += wa * gi;
            ar[lft + 1] += wb * gr;  ai[lft + 1] += wb * gi;
        }
        for (int p = 0; p < 8; ++p) {
            sA[t * 16 + 2 * p]     = ar[p];
            sA[t * 16 + 2 * p + 1] = ai[p];
        }
    }
    asm volatile("s_waitcnt lgkmcnt(0)" ::: "memory");
    __builtin_amdgcn_sched_barrier(0);
    if (t < 64) {   // MP build (values verbatim R22/R23), slim stride 16
        #pragma unroll
        for (int j = 0; j < 32; ++j) {
            int idx = t * 32 + j;
            int row = idx >> 4, k = idx & 15;
            int mm = row >> 1, s = row & 1;
            int p = k >> 1, u = k & 1;
            float Ar = sA[mm * 16 + 2 * p], Ai = sA[mm * 16 + 2 * p + 1];
            float val = (s == 0) ? ((u == 0) ? Ar : -Ai)
                                 : ((u == 0) ? Ai :  Ar);
            sT[T_MP + row * 16 + k] = f2bf(val);
        }
    }
    __syncthreads();   // SINGLE block barrier: all tables + MP visible

    // ---- Layer 1: bias as C-operand; B-side masking enforces K=16 ----
    pk_t h1a[4], h1b[4];
    #pragma unroll
    for (int ks = 0; ks < 4; ++ks) {
        #pragma unroll
        for (int half = 0; half < 2; ++half) {
            int ct = 2 * ks + half;
            float4 bv = *(const float4*)(b1 + ks * 32 + kg * 8 + half * 4);
            f32x4 cin = { bv.x, bv.y, bv.z, bv.w };
            short8v wf = *(const short8v*)(sT + T_W1 + (ct * 16 + m) * 16 + kg * 8);
            f32x4 aA = __builtin_amdgcn_mfma_f32_16x16x32_bf16(wf, xb0m, cin, 0, 0, 0);
            f32x4 aB = __builtin_amdgcn_mfma_f32_16x16x32_bf16(wf, xb1m, cin, 0, 0, 0);
            h1a[ks].u[2 * half]     = cvtpk(fmaxf(aA[0], 0.f), fmaxf(aA[1], 0.f));
            h1a[ks].u[2 * half + 1] = cvtpk(fmaxf(aA[2], 0.f), fmaxf(aA[3], 0.f));
            h1b[ks].u[2 * half]     = cvtpk(fmaxf(aB[0], 0.f), fmaxf(aB[1], 0.f));
            h1b[ks].u[2 * half + 1] = cvtpk(fmaxf(aB[2], 0.f), fmaxf(aB[3], 0.f));
        }
    }

    // ---- Layer 2: bias C-init ----
    f32x4 a2a[8], a2b[8];
    #pragma unroll
    for (int ct = 0; ct < 8; ++ct) {
        float4 bv = *(const float4*)(b2 + 32 * (ct >> 1) + 8 * kg + 4 * (ct & 1));
        f32x4 cin = { bv.x, bv.y, bv.z, bv.w };
        a2a[ct] = cin; a2b[ct] = cin;
    }
    #pragma unroll
    for (int ks = 0; ks < 4; ++ks) {
        short8v hfa = h1a[ks].v, hfb = h1b[ks].v;
        #pragma unroll
        for (int ct = 0; ct < 8; ++ct) {
            short8v wf = *(const short8v*)(sT + T_W2 + (ct * 16 + m) * 136 + ks * 32 + kg * 8);
            a2a[ct] = __builtin_amdgcn_mfma_f32_16x16x32_bf16(wf, hfa, a2a[ct], 0, 0, 0);
            a2b[ct] = __builtin_amdgcn_mfma_f32_16x16x32_bf16(wf, hfb, a2b[ct], 0, 0, 0);
        }
    }

    // ---- repack -> h2 ----
    pk_t h2a[4], h2b[4];
    #pragma unroll
    for (int ks = 0; ks < 4; ++ks) {
        #pragma unroll
        for (int half = 0; half < 2; ++half) {
            int ct = 2 * ks + half;
            h2a[ks].u[2 * half]     = cvtpk(fmaxf(a2a[ct][0], 0.f), fmaxf(a2a[ct][1], 0.f));
            h2a[ks].u[2 * half + 1] = cvtpk(fmaxf(a2a[ct][2], 0.f), fmaxf(a2a[ct][3], 0.f));
            h2b[ks].u[2 * half]     = cvtpk(fmaxf(a2b[ct][0], 0.f), fmaxf(a2b[ct][1], 0.f));
            h2b[ks].u[2 * half + 1] = cvtpk(fmaxf(a2b[ct][2], 0.f), fmaxf(a2b[ct][3], 0.f));
        }
    }

    // ---- Layer 3: b3 folded as C-init ----
    float4 b3c = *(const float4*)(b3 + 4 * kg);
    f32x4 cin3 = { b3c.x, b3c.y, b3c.z, b3c.w };
    f32x4 acc3a = cin3, acc3b = cin3;
    #pragma unroll
    for (int ks = 0; ks < 4; ++ks) {
        short8v wf = *(const short8v*)(sT + T_W3 + m * 136 + ks * 32 + kg * 8);
        acc3a = __builtin_amdgcn_mfma_f32_16x16x32_bf16(wf, h2a[ks].v, acc3a, 0, 0, 0);
        acc3b = __builtin_amdgcn_mfma_f32_16x16x32_bf16(wf, h2b[ks].v, acc3b, 0, 0, 0);
    }

    // ---- comb (R16/R21/R22/R23-proven lane algebra) ----
    pk_t myv;
    {
        float w0 = est_w[0];
        float al = fminf(fmaxf(alpha[0], 0.f), 1.f);
        float oma = 1.0f - al;
        bool low = (kg < 2);
        #pragma unroll
        for (int r = 0; r < 4; ++r) {
            float s0 = __shfl_xor(acc3a[r], 32);
            float s1 = __shfl_xor(acc3b[r], 32);
            float olow  = low ? acc3a[r] : s1;
            float ohigh = low ? s0 : acc3b[r];
            float cr = al * (lsv[2 * r] * w0)     + oma * fast_tanh(olow);
            float ci = al * (lsv[2 * r + 1] * w0) + oma * fast_tanh(ohigh);
            myv.u[r] = cvtpk(cr, ci);
        }
    }
    short8v vb1f;
    {
        union { short8v v; int i[4]; } ua, ub;
        ua.v = myv.v;
        #pragma unroll
        for (int q = 0; q < 4; ++q) ub.i[q] = __shfl_xor(ua.i[q], 32);
        vb1f = ub.v;
    }
    short8v vb0m = act ? myv.v : zz8;   // B-side masking for K=16
    short8v vb1m = act ? vb1f  : zz8;

    // ---- epilogue: MP fragments once (slim stride), MFMA+store bursts ----
    short8v mf[8];
    #pragma unroll
    for (int ct = 0; ct < 8; ++ct)
        mf[ct] = *(const short8v*)(sT + T_MP + (ct * 16 + m) * 16 + kg * 8);

    long e0 = base + m, e1 = base + 16 + m;
    float* orow0 = out + e0 * 128;
    float* orow1 = out + e1 * 128;
    {
        f32x4 eacc[8];
        #pragma unroll
        for (int ct = 0; ct < 8; ++ct)
            eacc[ct] = __builtin_amdgcn_mfma_f32_16x16x32_bf16(mf[ct], vb0m, z4, 0, 0, 0);
        if (e0 < B) {
            #pragma unroll
            for (int ct = 0; ct < 8; ++ct) {
                float4 st = { eacc[ct][0], eacc[ct][1], eacc[ct][2], eacc[ct][3] };
                *(float4*)(orow0 + ct * 16 + kg * 4) = st;
            }
        }
        #pragma unroll
        for (int ct = 0; ct < 8; ++ct)
            eacc[ct] = __builtin_amdgcn_mfma_f32_16x16x32_bf16(mf[ct], vb1m, z4, 0, 0, 0);
        if (e1 < B) {
            #pragma unroll
            for (int ct = 0; ct < 8; ++ct) {
                float4 st = { eacc[ct][0], eacc[ct][1], eacc[ct][2], eacc[ct][3] };
                *(float4*)(orow1 + ct * 16 + kg * 4) = st;
            }
        }
    }
}

extern "C" void kernel_launch(void* const* d_in, const int* in_sizes, int n_in,
                              void* d_out, int out_size, void* d_ws, size_t ws_size,
                              hipStream_t stream) {
    const float* Y             = (const float*)d_in[0];
    const float* Xp            = (const float*)d_in[1];
    const int*   pilot_pos     = (const int*)d_in[2];
    const float* W1            = (const float*)d_in[3];
    const float* b1            = (const float*)d_in[4];
    const float* W2            = (const float*)d_in[5];
    const float* b2            = (const float*)d_in[6];
    const float* W3            = (const float*)d_in[7];
    const float* b3            = (const float*)d_in[8];
    const float* est_w         = (const float*)d_in[9];
    const float* alpha         = (const float*)d_in[10];
    const float* decay_param   = (const float*)d_in[11];
    const float* window_logits = (const float*)d_in[12];
    float* out = (float*)d_out;

    int B = in_sizes[0] / 128;
    int grid = (B + 255) / 256;
    hipLaunchKernelGGL(ce_all, dim3(grid), dim3(512), 0, stream,
                       Y, Xp, pilot_pos, W1, b1, W2, b2, W3, b3,
                       est_w, alpha, decay_param, window_logits, out, B);
}

// Round 25
// 51.528 us; speedup vs baseline: 1.5730x; 1.5730x over previous
//
#include <hip/hip_runtime.h>
#include <hip/hip_bf16.h>
#include <math.h>

typedef __attribute__((ext_vector_type(8))) short short8v;   // 8 bf16 bits
typedef __attribute__((ext_vector_type(4))) float f32x4;     // 16x16 MFMA acc

__device__ __forceinline__ unsigned short f2bf(float x) {
    union { float f; unsigned u; } v; v.f = x;
    unsigned r = v.u + 0x7FFF + ((v.u >> 16) & 1);   // RNE
    return (unsigned short)(r >> 16);
}
__device__ __forceinline__ unsigned cvtpk(float a, float b) {
    unsigned short lo = __builtin_bit_cast(unsigned short, __float2bfloat16(a));
    unsigned short hi = __builtin_bit_cast(unsigned short, __float2bfloat16(b));
    return (unsigned)lo | ((unsigned)hi << 16);
}
__device__ __forceinline__ float fast_tanh(float x) {
    float e = __expf(2.0f * x);
    return 1.0f - 2.0f / (e + 1.0f);
}
// sigma(ct,p) = 32*(ct>>1) + 8*(p>>2) + 4*(ct&1) + (p&3); row = ct*16+p.
// Inverse (R22-verified): col bits [c2 c1 p3 p2 c0 p1 p0]
__device__ __forceinline__ int sigma_inv_row(int col) {
    int ct = ((col >> 4) & 6) | ((col >> 2) & 1);
    int p  = ((col >> 1) & 12) | (col & 3);
    return ct * 16 + p;
}

// LDS table layout (shorts) — R18/R21/R22/R23-proven padded strides
// (stride 40 = 80 B keeps W1/MP ds_read_b128 ~2-way conflict-free; R24's
// slim stride 16 = 32 B was a 4-8-way conflict and regressed 52->81 us):
//   T_W1  [128 row][40]  k<16 = W1[k][sigma], k16..31 ZERO  (5120 sh)
//   T_W2  [128 row][136] k<128 = W2[k][sigma]               (17408 sh)
//   T_W3  [16 col][136]  k<128 = W3[k][col]                 (2176 sh)
//   T_MP  [128 row][40]  k<16 = MP val, k16..31 ZERO        (5120 sh)
#define T_W1    0
#define T_W2    5120
#define T_W3    22528
#define T_MP    24704
#define T_SH    29824          // 59648 B

// ---------------------------------------------------------------------------
// SINGLE kernel (R23, best measured 52.1 us): float4 stage reads,
// single-barrier A/MP build (wave-0-internal, rule #18 fences), dual-tile
// register MLP. 512 thr, 256 elems/block, grid = 512 (all co-resident).
// ---------------------------------------------------------------------------
__global__ __launch_bounds__(512) void ce_all(
    const float* __restrict__ Y, const float* __restrict__ Xp,
    const int* __restrict__ pilot_pos,
    const float* __restrict__ W1, const float* __restrict__ b1,
    const float* __restrict__ W2, const float* __restrict__ b2,
    const float* __restrict__ W3, const float* __restrict__ b3,
    const float* __restrict__ est_w, const float* __restrict__ alpha,
    const float* __restrict__ decay_param,
    const float* __restrict__ window_logits,
    float* __restrict__ out, int B)
{
    __shared__ unsigned short sT[T_SH];          // 59648 B
    __shared__ float sA[64 * 16];                // 4096 B
    __shared__ float Gr[64], Gi[64], wln[64], wrn[64];
    __shared__ int lefts[64];

    const int t = threadIdx.x;
    const int w = t >> 6, l = t & 63;
    const int m = l & 15, kg = l >> 4;
    const int tl = kg >> 1, pg = kg & 1;
    const long base = (long)blockIdx.x * 256 + w * 32;

    typedef union { unsigned u[4]; short8v v; } pk_t;
    const f32x4 z4 = {0.f, 0.f, 0.f, 0.f};

    // ---- gather (ALL 64 lanes) issued first; hides under table build ----
    long e_g = base + tl * 16 + m;
    long e_gc = (e_g < B) ? e_g : (long)(B - 1);
    const float* yrow = Y + e_gc * 128;
    const float4* xr = (const float4*)(Xp + e_gc * 16 + pg * 8);
    int p0 = pg * 4;
    float2 y0 = *(const float2*)(yrow + pilot_pos[p0 + 0] * 2);
    float2 y1 = *(const float2*)(yrow + pilot_pos[p0 + 1] * 2);
    float2 y2 = *(const float2*)(yrow + pilot_pos[p0 + 2] * 2);
    float2 y3 = *(const float2*)(yrow + pilot_pos[p0 + 3] * 2);
    float4 x0 = xr[0], x1 = xr[1];

    // ---- stage W1/W2/W3: float4 global reads, scattered LDS writes ----
    {   // W1: 2048 floats = 512 float4 -> one per thread
        float4 v = ((const float4*)W1)[t];
        int k = t >> 5, c4 = (t & 31) * 4;
        sT[T_W1 + sigma_inv_row(c4 + 0) * 40 + k] = f2bf(v.x);
        sT[T_W1 + sigma_inv_row(c4 + 1) * 40 + k] = f2bf(v.y);
        sT[T_W1 + sigma_inv_row(c4 + 2) * 40 + k] = f2bf(v.z);
        sT[T_W1 + sigma_inv_row(c4 + 3) * 40 + k] = f2bf(v.w);
    }
    #pragma unroll
    for (int ii = 0; ii < 8; ++ii) {   // W2: 4096 float4
        int i = ii * 512 + t;
        float4 v = ((const float4*)W2)[i];
        int k = i >> 5, c4 = (i & 31) * 4;
        sT[T_W2 + sigma_inv_row(c4 + 0) * 136 + k] = f2bf(v.x);
        sT[T_W2 + sigma_inv_row(c4 + 1) * 136 + k] = f2bf(v.y);
        sT[T_W2 + sigma_inv_row(c4 + 2) * 136 + k] = f2bf(v.z);
        sT[T_W2 + sigma_inv_row(c4 + 3) * 136 + k] = f2bf(v.w);
    }
    {   // W3 cols 0..15: 128 rows x 4 float4 = 512 -> one per thread
        int k = t >> 2, c4 = (t & 3) * 4;
        float4 v = *(const float4*)(W3 + k * 64 + c4);
        sT[T_W3 + (c4 + 0) * 136 + k] = f2bf(v.x);
        sT[T_W3 + (c4 + 1) * 136 + k] = f2bf(v.y);
        sT[T_W3 + (c4 + 2) * 136 + k] = f2bf(v.z);
        sT[T_W3 + (c4 + 3) * 136 + k] = f2bf(v.w);
    }
    for (int i = t; i < 2048; i += 512)   // W1 zero pad k16..31
        sT[T_W1 + (i >> 4) * 40 + 16 + (i & 15)] = 0;
    for (int i = t; i < 2048; i += 512)   // MP zero pad k16..31
        sT[T_MP + (i >> 4) * 40 + 16 + (i & 15)] = 0;

    // ---- LS compute + pack (register-only; |Xp|=1 -> no division) ----
    float lsv[8];
    {
        lsv[0] = y0.x * x0.x + y0.y * x0.y;
        lsv[1] = y0.y * x0.x - y0.x * x0.y;
        lsv[2] = y1.x * x0.z + y1.y * x0.w;
        lsv[3] = y1.y * x0.z - y1.x * x0.w;
        lsv[4] = y2.x * x1.x + y2.y * x1.y;
        lsv[5] = y2.y * x1.x - y2.x * x1.y;
        lsv[6] = y3.x * x1.z + y3.y * x1.w;
        lsv[7] = y3.y * x1.z - y3.x * x1.w;
    }
    pk_t px;
    px.u[0] = cvtpk(lsv[0], lsv[1]);
    px.u[1] = cvtpk(lsv[2], lsv[3]);
    px.u[2] = cvtpk(lsv[4], lsv[5]);
    px.u[3] = cvtpk(lsv[6], lsv[7]);
    short8v xb = px.v;
    short8v xb1;
    {
        union { short8v v; int i[4]; } ua, ub;
        ua.v = xb;
        #pragma unroll
        for (int q = 0; q < 4; ++q) ub.i[q] = __shfl_xor(ua.i[q], 32);
        xb1 = ub.v;
    }

    // ---- A/MP build: WAVE 0 ONLY (t<64), intra-wave LDS ordering ----
    if (t < 64) {
        float decay = log1pf(expf(decay_param[0]));
        float winv[8];
        int posv[8];
        #pragma unroll
        for (int n = 0; n < 8; ++n) {
            winv[n] = 1.0f / (1.0f + expf(-window_logits[n]));
            posv[n] = pilot_pos[n];
        }
        float gr = 0.f, gi = 0.f;
        #pragma unroll
        for (int n = 0; n < 8; ++n) {
            float ang = 6.283185307179586f * (float)(n * t) * (1.0f / 64.0f);
            gr += winv[n] * cosf(ang);
            gi += winv[n] * sinf(ang);
        }
        Gr[t] = gr * (1.0f / 64.0f);
        Gi[t] = gi * (1.0f / 64.0f);
        int lft = 0;
        #pragma unroll
        for (int p = 1; p < 8; ++p) if (posv[p] <= t) lft = p;
        if (lft > 6) lft = 6;
        float xx0 = (float)posv[lft], xx1 = (float)posv[lft + 1], fi = (float)t;
        float wl = expf(-decay * fabsf(fi - xx0));
        float wr = expf(-decay * fabsf(xx1 - fi));
        float wsum = wl + wr + 1e-12f;
        lefts[t] = lft; wln[t] = wl / wsum; wrn[t] = wr / wsum;
    }
    asm volatile("s_waitcnt lgkmcnt(0)" ::: "memory");
    __builtin_amdgcn_sched_barrier(0);
    if (t < 64) {
        float ar[8], ai[8];
        for (int p = 0; p < 8; ++p) { ar[p] = 0.f; ai[p] = 0.f; }
        for (int i = 0; i < 64; ++i) {
            int d = (i - t) & 63;
            float gr = Gr[d], gi = Gi[d];
            int lft = lefts[i];
            float wa = wln[i], wb = wrn[i];
            ar[lft]     += wa * gr;  ai[lft]     += wa * gi;
            ar[lft + 1] += wb * gr;  ai[lft + 1] += wb * gi;
        }
        for (int p = 0; p < 8; ++p) {
            sA[t * 16 + 2 * p]     = ar[p];
            sA[t * 16 + 2 * p + 1] = ai[p];
        }
    }
    asm volatile("s_waitcnt lgkmcnt(0)" ::: "memory");
    __builtin_amdgcn_sched_barrier(0);
    if (t < 64) {   // MP build, 32 entries/lane (padded stride 40)
        #pragma unroll
        for (int j = 0; j < 32; ++j) {
            int idx = t * 32 + j;
            int row = idx >> 4, k = idx & 15;
            int mm = row >> 1, s = row & 1;
            int p = k >> 1, u = k & 1;
            float Ar = sA[mm * 16 + 2 * p], Ai = sA[mm * 16 + 2 * p + 1];
            float val = (s == 0) ? ((u == 0) ? Ar : -Ai)
                                 : ((u == 0) ? Ai :  Ar);
            sT[T_MP + row * 40 + k] = f2bf(val);
        }
    }
    __syncthreads();   // SINGLE block barrier: all tables + MP visible

    // ---- Layer 1: bias as C-operand ----
    pk_t h1a[4], h1b[4];
    #pragma unroll
    for (int ks = 0; ks < 4; ++ks) {
        #pragma unroll
        for (int half = 0; half < 2; ++half) {
            int ct = 2 * ks + half;
            float4 bv = *(const float4*)(b1 + ks * 32 + kg * 8 + half * 4);
            f32x4 cin = { bv.x, bv.y, bv.z, bv.w };
            short8v wf = *(const short8v*)(sT + T_W1 + (ct * 16 + m) * 40 + kg * 8);
            f32x4 aA = __builtin_amdgcn_mfma_f32_16x16x32_bf16(wf, xb,  cin, 0, 0, 0);
            f32x4 aB = __builtin_amdgcn_mfma_f32_16x16x32_bf16(wf, xb1, cin, 0, 0, 0);
            h1a[ks].u[2 * half]     = cvtpk(fmaxf(aA[0], 0.f), fmaxf(aA[1], 0.f));
            h1a[ks].u[2 * half + 1] = cvtpk(fmaxf(aA[2], 0.f), fmaxf(aA[3], 0.f));
            h1b[ks].u[2 * half]     = cvtpk(fmaxf(aB[0], 0.f), fmaxf(aB[1], 0.f));
            h1b[ks].u[2 * half + 1] = cvtpk(fmaxf(aB[2], 0.f), fmaxf(aB[3], 0.f));
        }
    }

    // ---- Layer 2: bias C-init ----
    f32x4 a2a[8], a2b[8];
    #pragma unroll
    for (int ct = 0; ct < 8; ++ct) {
        float4 bv = *(const float4*)(b2 + 32 * (ct >> 1) + 8 * kg + 4 * (ct & 1));
        f32x4 cin = { bv.x, bv.y, bv.z, bv.w };
        a2a[ct] = cin; a2b[ct] = cin;
    }
    #pragma unroll
    for (int ks = 0; ks < 4; ++ks) {
        short8v hfa = h1a[ks].v, hfb = h1b[ks].v;
        #pragma unroll
        for (int ct = 0; ct < 8; ++ct) {
            short8v wf = *(const short8v*)(sT + T_W2 + (ct * 16 + m) * 136 + ks * 32 + kg * 8);
            a2a[ct] = __builtin_amdgcn_mfma_f32_16x16x32_bf16(wf, hfa, a2a[ct], 0, 0, 0);
            a2b[ct] = __builtin_amdgcn_mfma_f32_16x16x32_bf16(wf, hfb, a2b[ct], 0, 0, 0);
        }
    }

    // ---- repack -> h2 ----
    pk_t h2a[4], h2b[4];
    #pragma unroll
    for (int ks = 0; ks < 4; ++ks) {
        #pragma unroll
        for (int half = 0; half < 2; ++half) {
            int ct = 2 * ks + half;
            h2a[ks].u[2 * half]     = cvtpk(fmaxf(a2a[ct][0], 0.f), fmaxf(a2a[ct][1], 0.f));
            h2a[ks].u[2 * half + 1] = cvtpk(fmaxf(a2a[ct][2], 0.f), fmaxf(a2a[ct][3], 0.f));
            h2b[ks].u[2 * half]     = cvtpk(fmaxf(a2b[ct][0], 0.f), fmaxf(a2b[ct][1], 0.f));
            h2b[ks].u[2 * half + 1] = cvtpk(fmaxf(a2b[ct][2], 0.f), fmaxf(a2b[ct][3], 0.f));
        }
    }

    // ---- Layer 3: b3 folded as C-init ----
    float4 b3c = *(const float4*)(b3 + 4 * kg);
    f32x4 cin3 = { b3c.x, b3c.y, b3c.z, b3c.w };
    f32x4 acc3a = cin3, acc3b = cin3;
    #pragma unroll
    for (int ks = 0; ks < 4; ++ks) {
        short8v wf = *(const short8v*)(sT + T_W3 + m * 136 + ks * 32 + kg * 8);
        acc3a = __builtin_amdgcn_mfma_f32_16x16x32_bf16(wf, h2a[ks].v, acc3a, 0, 0, 0);
        acc3b = __builtin_amdgcn_mfma_f32_16x16x32_bf16(wf, h2b[ks].v, acc3b, 0, 0, 0);
    }

    // ---- comb (R16/R21/R22/R23-proven lane algebra) ----
    pk_t myv;
    {
        float w0 = est_w[0];
        float al = fminf(fmaxf(alpha[0], 0.f), 1.f);
        float oma = 1.0f - al;
        bool low = (kg < 2);
        #pragma unroll
        for (int r = 0; r < 4; ++r) {
            float s0 = __shfl_xor(acc3a[r], 32);
            float s1 = __shfl_xor(acc3b[r], 32);
            float olow  = low ? acc3a[r] : s1;
            float ohigh = low ? s0 : acc3b[r];
            float cr = al * (lsv[2 * r] * w0)     + oma * fast_tanh(olow);
            float ci = al * (lsv[2 * r + 1] * w0) + oma * fast_tanh(ohigh);
            myv.u[r] = cvtpk(cr, ci);
        }
    }
    short8v vb0 = myv.v;
    short8v vb1;
    {
        union { short8v v; int i[4]; } ua, ub;
        ua.v = myv.v;
        #pragma unroll
        for (int q = 0; q < 4; ++q) ub.i[q] = __shfl_xor(ua.i[q], 32);
        vb1 = ub.v;
    }

    // ---- epilogue: MP fragments once, MFMA+store bursts per tile ----
    short8v mf[8];
    #pragma unroll
    for (int ct = 0; ct < 8; ++ct)
        mf[ct] = *(const short8v*)(sT + T_MP + (ct * 16 + m) * 40 + kg * 8);

    long e0 = base + m, e1 = base + 16 + m;
    float* orow0 = out + e0 * 128;
    float* orow1 = out + e1 * 128;
    {
        f32x4 eacc[8];
        #pragma unroll
        for (int ct = 0; ct < 8; ++ct)
            eacc[ct] = __builtin_amdgcn_mfma_f32_16x16x32_bf16(mf[ct], vb0, z4, 0, 0, 0);
        if (e0 < B) {
            #pragma unroll
            for (int ct = 0; ct < 8; ++ct) {
                float4 st = { eacc[ct][0], eacc[ct][1], eacc[ct][2], eacc[ct][3] };
                *(float4*)(orow0 + ct * 16 + kg * 4) = st;
            }
        }
        #pragma unroll
        for (int ct = 0; ct < 8; ++ct)
            eacc[ct] = __builtin_amdgcn_mfma_f32_16x16x32_bf16(mf[ct], vb1, z4, 0, 0, 0);
        if (e1 < B) {
            #pragma unroll
            for (int ct = 0; ct < 8; ++ct) {
                float4 st = { eacc[ct][0], eacc[ct][1], eacc[ct][2], eacc[ct][3] };
                *(float4*)(orow1 + ct * 16 + kg * 4) = st;
            }
        }
    }
}

extern "C" void kernel_launch(void* const* d_in, const int* in_sizes, int n_in,
                              void* d_out, int out_size, void* d_ws, size_t ws_size,
                              hipStream_t stream) {
    const float* Y             = (const float*)d_in[0];
    const float* Xp            = (const float*)d_in[1];
    const int*   pilot_pos     = (const int*)d_in[2];
    const float* W1            = (const float*)d_in[3];
    const float* b1            = (const float*)d_in[4];
    const float* W2            = (const float*)d_in[5];
    const float* b2            = (const float*)d_in[6];
    const float* W3            = (const float*)d_in[7];
    const float* b3            = (const float*)d_in[8];
    const float* est_w         = (const float*)d_in[9];
    const float* alpha         = (const float*)d_in[10];
    const float* decay_param   = (const float*)d_in[11];
    const float* window_logits = (const float*)d_in[12];
    float* out = (float*)d_out;

    int B = in_sizes[0] / 128;
    int grid = (B + 255) / 256;
    hipLaunchKernelGGL(ce_all, dim3(grid), dim3(512), 0, stream,
                       Y, Xp, pilot_pos, W1, b1, W2, b2, W3, b3,
                       est_w, alpha, decay_param, window_logits, out, B);
}